// Round 9
// baseline (378.929 us; speedup 1.0000x reference)
//
#include <hip/hip_runtime.h>

// DEQ fused: out = relu^{(30)}(z Wz^T + inj) @ Wd^T + bd, inj = x Ux^T + b
//
// Round-9: keep round-8's occupancy (4 waves/SIMD, ~126 unified regs/wave),
// halve the LDS traffic. Wave split goes 4-way-n -> 2n x 2m:
//   wave (wn, wm): n-half [64wn, 64wn+64) x m-half [16wm, 16wm+16)
//   per wave/iter: 4nt x 1mt x 4ks = 16 MFMA (same as round 8)
//   LDS reads 8 -> 4 b128/wave-iter; block-iter 40KB -> 24KB
// Ledger (per CU): MFMA 308k cy vs LDS ~267k cy -> matrix pipe binds again,
// with 16 waves/CU to overlap. Round 8 measured LDS-bound: 445k cy LDS vs
// 308k MFMA -> MfmaUtil stuck at 48.
// SQ_LDS_BANK_CONFLICT == inherent wave64 b128 phasing (invariant across
// layouts, rounds 0/2/7); expect ~3.1e7 tracking the halved read count.
// Registers: awz 64 (acc-file) + inj 16 + acc 16 + bz 16 + misc ~= 126.

typedef __attribute__((ext_vector_type(8))) __bf16 bf16x8;
typedef __attribute__((ext_vector_type(4))) __bf16 bf16x4;
typedef __attribute__((ext_vector_type(4))) float  floatx4;

#define MFMA16(a, b, c) __builtin_amdgcn_mfma_f32_16x16x32_bf16((a), (b), (c), 0, 0, 0)

static constexpr int kBsz = 262144;
static constexpr int kTM  = 32;    // batch rows per block

__device__ __forceinline__ bf16x8 cvt_bf16x8(float4 a, float4 b) {
  bf16x8 r;
  r[0] = (__bf16)a.x; r[1] = (__bf16)a.y; r[2] = (__bf16)a.z; r[3] = (__bf16)a.w;
  r[4] = (__bf16)b.x; r[5] = (__bf16)b.y; r[6] = (__bf16)b.z; r[7] = (__bf16)b.w;
  return r;
}

__global__ void __launch_bounds__(256, 4) deq_fused(
    const float* __restrict__ x,    // [B,64]
    const float* __restrict__ Wz,   // [128,128]
    const float* __restrict__ Ux,   // [128,64]
    const float* __restrict__ bvec, // [128]
    const float* __restrict__ Wd,   // [64,128]
    const float* __restrict__ bd,   // [64]
    const int*  __restrict__ n_iters_p,
    float* __restrict__ out)        // [B,64]
{
  // double-buffered z tile, row-major [m][n], stride 136 bf16 = 272 B
  __shared__ __align__(16) __bf16 zl[2][kTM][136];   // 17408 B

  const int tid  = threadIdx.x;
  const int lane = tid & 63;
  const int wv   = tid >> 6;   // 0..3
  const int wn   = wv & 1;     // n-half: hid units [64*wn, 64*wn+64)
  const int wm   = wv >> 1;    // m-half: rows [16*wm, 16*wm+16)
  const int l15  = lane & 15;
  const int quad = lane >> 4;  // 0..3
  const int row0 = blockIdx.x * kTM;
  const int ml   = 16 * wm + l15;   // this wave's local m row
  const int iters = *n_iters_p;

  // ---- Wz as A-fragments (iteration-invariant, 64 regs in acc file) ----
  // A[n][k]: n = 64*wn + 16*nt + l15, k = 32*ks + 8*quad + j
  bf16x8 awz[4][4];
#pragma unroll
  for (int nt = 0; nt < 4; ++nt) {
    const int n = 64 * wn + 16 * nt + l15;
#pragma unroll
    for (int ks = 0; ks < 4; ++ks) {
      const float4* p = (const float4*)(Wz + n * 128 + 32 * ks + 8 * quad);
      awz[nt][ks] = cvt_bf16x8(p[0], p[1]);
    }
  }

  // ---- inj^T in C/D layout: inj[nt], reg i -> n = 64wn+16nt+4quad+i ----
  floatx4 inj[4];
#pragma unroll
  for (int nt = 0; nt < 4; ++nt) {
    const float4 bv = *(const float4*)(bvec + 64 * wn + 16 * nt + 4 * quad);
    floatx4 v = {bv.x, bv.y, bv.z, bv.w};
    inj[nt] = v;
  }
  {
    // x^T as B-frag for this wave's m-half (K=64 -> 2 k-steps)
    bf16x8 bx[2];
#pragma unroll
    for (int ks = 0; ks < 2; ++ks) {
      const float4* p = (const float4*)(x + (size_t)(row0 + ml) * 64 + 32 * ks + 8 * quad);
      bx[ks] = cvt_bf16x8(p[0], p[1]);
    }
#pragma unroll
    for (int nt = 0; nt < 4; ++nt) {
      const int n = 64 * wn + 16 * nt + l15;
#pragma unroll
      for (int ks = 0; ks < 2; ++ks) {
        const float4* p = (const float4*)(Ux + n * 64 + 32 * ks + 8 * quad);
        const bf16x8 a = cvt_bf16x8(p[0], p[1]);
        inj[nt] = MFMA16(a, bx[ks], inj[nt]);
      }
    }
  }

  // ---- z1 = relu(inj) (z0 = 0) -> buffer 0, packed b64 writes ----
#pragma unroll
  for (int nt = 0; nt < 4; ++nt) {
    bf16x4 z4;
#pragma unroll
    for (int i = 0; i < 4; ++i) z4[i] = (__bf16)fmaxf(inj[nt][i], 0.0f);
    *(bf16x4*)&zl[0][ml][64 * wn + 16 * nt + 4 * quad] = z4;
  }

  // ---- fixed-point loop: 1 barrier per iteration (double buffer) ----
  int pb = 0;
  for (int t = 0; t < iters - 1; ++t) {
    __syncthreads();
    // full-k B-frags for this wave's m-half: 4 x ds_read_b128, one burst
    bf16x8 bz[4];
#pragma unroll
    for (int ks = 0; ks < 4; ++ks)
      bz[ks] = *(const bf16x8*)&zl[pb][ml][32 * ks + 8 * quad];
    const int nb = pb ^ 1;
#pragma unroll
    for (int nt = 0; nt < 4; ++nt) {
      floatx4 acc = inj[nt];
#pragma unroll
      for (int ks = 0; ks < 4; ++ks)
        acc = MFMA16(awz[nt][ks], bz[ks], acc);
      bf16x4 z4;
#pragma unroll
      for (int i = 0; i < 4; ++i) z4[i] = (__bf16)fmaxf(acc[i], 0.0f);
      // reg axis i is consecutive n -> one ds_write_b64
      *(bf16x4*)&zl[nb][ml][64 * wn + 16 * nt + 4 * quad] = z4;
    }
    pb = nb;
  }
  __syncthreads();

  // ---- decoder: D[o][m] = sum_k Wd[o][k] Z^T[k][m] + bd ----
  // wave (wn, wm) -> o-half 32*wn, m rows 16*wm (same ml as loop)
  bf16x8 awd[2][4];
#pragma unroll
  for (int ot = 0; ot < 2; ++ot) {
    const int o = 32 * wn + 16 * ot + l15;
#pragma unroll
    for (int ks = 0; ks < 4; ++ks) {
      const float4* p = (const float4*)(Wd + o * 128 + 32 * ks + 8 * quad);
      awd[ot][ks] = cvt_bf16x8(p[0], p[1]);
    }
  }
  {
    bf16x8 bz[4];
#pragma unroll
    for (int ks = 0; ks < 4; ++ks)
      bz[ks] = *(const bf16x8*)&zl[pb][ml][32 * ks + 8 * quad];
#pragma unroll
    for (int ot = 0; ot < 2; ++ot) {
      const float4 bv = *(const float4*)(bd + 32 * wn + 16 * ot + 4 * quad);
      floatx4 acc = {bv.x, bv.y, bv.z, bv.w};
#pragma unroll
      for (int ks = 0; ks < 4; ++ks)
        acc = MFMA16(awd[ot][ks], bz[ks], acc);
      // reg i -> consecutive o: one dwordx4 global store
      float4 ov;
      ov.x = acc[0]; ov.y = acc[1]; ov.z = acc[2]; ov.w = acc[3];
      *(float4*)(out + (size_t)(row0 + ml) * 64 + 32 * wn + 16 * ot + 4 * quad) = ov;
    }
  }
}

extern "C" void kernel_launch(void* const* d_in, const int* in_sizes, int n_in,
                              void* d_out, int out_size, void* d_ws, size_t ws_size,
                              hipStream_t stream) {
  const float* x  = (const float*)d_in[0];
  const float* Wz = (const float*)d_in[1];
  const float* Ux = (const float*)d_in[2];
  const float* b  = (const float*)d_in[3];
  const float* Wd = (const float*)d_in[4];
  const float* bd = (const float*)d_in[5];
  const int* n_it = (const int*)d_in[6];
  float* outp = (float*)d_out;
  (void)in_sizes; (void)n_in; (void)d_ws; (void)ws_size; (void)out_size;

  dim3 grid(kBsz / kTM);  // 8192 blocks of 256 threads
  deq_fused<<<grid, 256, 0, stream>>>(x, Wz, Ux, b, Wd, bd, n_it, outp);
}

// Round 10
// 366.614 us; speedup vs baseline: 1.0336x; 1.0336x over previous
//
#include <hip/hip_runtime.h>

// DEQ fused: out = relu^{(30)}(z Wz^T + inj) @ Wd^T + bd, inj = x Ux^T + b
//
// Round-10: round-9's 2n x 2m wave mapping (half the LDS traffic of round 8:
// 288 cy/block-iter, amp 2x) with a register diet to reach round-8's
// occupancy (4 waves/SIMD). Round 9 measured ~153 unified regs/wave
// (awz 64 AGPR + 64 VGPR + acc-file spillover) -> 3.4 waves/SIMD -> 35.7%
// MfmaUtil. Cross-round law (r7/r8/r9): T_iter ~2600-2800 cy invariant;
// throughput ~ resident waves x MFMA/wave. Target: total <= 128 regs.
//   1. compile-time double buffer (2x unrolled STEP, no pb reg, all LDS
//      addresses = per-lane base + immediate offset)
//   2. two precomputed LDS byte bases (read, write)
//   3. per-ks B-read placement (read -> 4 MFMA -> read), bz live = 1 frag
// Mapping (unchanged, verified r9): wave (wn,wm) owns n-half x 16 rows;
// per iter 4nt x 4ks = 16 MFMA, 4 ds_read_b128, 4 ds_write_b64.
// SQ_LDS_BANK_CONFLICT == b128-read count x 8 (inherent wave64 phasing,
// invariant across layouts r0/r2/r7) — not a lever.

typedef __attribute__((ext_vector_type(8))) __bf16 bf16x8;
typedef __attribute__((ext_vector_type(4))) __bf16 bf16x4;
typedef __attribute__((ext_vector_type(4))) float  floatx4;

#define MFMA16(a, b, c) __builtin_amdgcn_mfma_f32_16x16x32_bf16((a), (b), (c), 0, 0, 0)

static constexpr int kBsz = 262144;
static constexpr int kTM  = 32;            // batch rows per block
static constexpr int kLd  = 136;           // z row stride (bf16 elems)
static constexpr int kBufElems = kTM * kLd;

__device__ __forceinline__ bf16x8 cvt_bf16x8(float4 a, float4 b) {
  bf16x8 r;
  r[0] = (__bf16)a.x; r[1] = (__bf16)a.y; r[2] = (__bf16)a.z; r[3] = (__bf16)a.w;
  r[4] = (__bf16)b.x; r[5] = (__bf16)b.y; r[6] = (__bf16)b.z; r[7] = (__bf16)b.w;
  return r;
}

__global__ void __launch_bounds__(256, 4) deq_fused(
    const float* __restrict__ x,    // [B,64]
    const float* __restrict__ Wz,   // [128,128]
    const float* __restrict__ Ux,   // [128,64]
    const float* __restrict__ bvec, // [128]
    const float* __restrict__ Wd,   // [64,128]
    const float* __restrict__ bd,   // [64]
    const int*  __restrict__ n_iters_p,
    float* __restrict__ out)        // [B,64]
{
  // double-buffered z tile, row-major [m][n], stride 136 bf16 = 272 B
  __shared__ __align__(16) __bf16 zl[2][kBufElems];   // 17408 B

  const int tid  = threadIdx.x;
  const int lane = tid & 63;
  const int wv   = tid >> 6;   // 0..3
  const int wn   = wv & 1;     // n-half: hid units [64*wn, 64*wn+64)
  const int wm   = wv >> 1;    // m-half: rows [16*wm, 16*wm+16)
  const int l15  = lane & 15;
  const int quad = lane >> 4;  // 0..3
  const int row0 = blockIdx.x * kTM;
  const int ml   = 16 * wm + l15;   // this wave's local m row
  const int iters = *n_iters_p;

  // per-lane LDS element offsets (buffer-relative); ks/nt folded as immediates
  const int rdo = ml * kLd + 8 * quad;             // + 32*ks
  const int wro = ml * kLd + 64 * wn + 4 * quad;   // + 16*nt

  // ---- Wz as A-fragments (iteration-invariant, 64 regs in acc file) ----
  // A[n][k]: n = 64*wn + 16*nt + l15, k = 32*ks + 8*quad + j
  bf16x8 awz[4][4];
#pragma unroll
  for (int nt = 0; nt < 4; ++nt) {
    const int n = 64 * wn + 16 * nt + l15;
#pragma unroll
    for (int ks = 0; ks < 4; ++ks) {
      const float4* p = (const float4*)(Wz + n * 128 + 32 * ks + 8 * quad);
      awz[nt][ks] = cvt_bf16x8(p[0], p[1]);
    }
  }

  // ---- inj^T in C/D layout: inj[nt], reg i -> n = 64wn+16nt+4quad+i ----
  floatx4 inj[4];
#pragma unroll
  for (int nt = 0; nt < 4; ++nt) {
    const float4 bv = *(const float4*)(bvec + 64 * wn + 16 * nt + 4 * quad);
    floatx4 v = {bv.x, bv.y, bv.z, bv.w};
    inj[nt] = v;
  }
  {
    // x^T as B-frag for this wave's m rows (K=64 -> 2 k-steps)
    bf16x8 bx[2];
#pragma unroll
    for (int ks = 0; ks < 2; ++ks) {
      const float4* p = (const float4*)(x + (size_t)(row0 + ml) * 64 + 32 * ks + 8 * quad);
      bx[ks] = cvt_bf16x8(p[0], p[1]);
    }
#pragma unroll
    for (int nt = 0; nt < 4; ++nt) {
      const int n = 64 * wn + 16 * nt + l15;
#pragma unroll
      for (int ks = 0; ks < 2; ++ks) {
        const float4* p = (const float4*)(Ux + n * 64 + 32 * ks + 8 * quad);
        const bf16x8 a = cvt_bf16x8(p[0], p[1]);
        inj[nt] = MFMA16(a, bx[ks], inj[nt]);
      }
    }
  }

  // ---- z1 = relu(inj) (z0 = 0) -> buffer 0, packed b64 writes ----
#pragma unroll
  for (int nt = 0; nt < 4; ++nt) {
    bf16x4 z4;
#pragma unroll
    for (int i = 0; i < 4; ++i) z4[i] = (__bf16)fmaxf(inj[nt][i], 0.0f);
    *(bf16x4*)&zl[0][wro + 16 * nt] = z4;
  }

  // ---- one fixed-point step: src buffer -> dst buffer (compile-time) ----
  auto STEP = [&](const __bf16* __restrict__ src, __bf16* __restrict__ dst) {
    __syncthreads();
    floatx4 acc[4];
#pragma unroll
    for (int nt = 0; nt < 4; ++nt) acc[nt] = inj[nt];
#pragma unroll
    for (int ks = 0; ks < 4; ++ks) {
      const bf16x8 b = *(const bf16x8*)&src[rdo + 32 * ks];
#pragma unroll
      for (int nt = 0; nt < 4; ++nt)
        acc[nt] = MFMA16(awz[nt][ks], b, acc[nt]);
    }
#pragma unroll
    for (int nt = 0; nt < 4; ++nt) {
      bf16x4 z4;
#pragma unroll
      for (int i = 0; i < 4; ++i) z4[i] = (__bf16)fmaxf(acc[nt][i], 0.0f);
      *(bf16x4*)&dst[wro + 16 * nt] = z4;   // reg axis i = consecutive n
    }
  };

  // ---- fixed-point loop: 1 barrier/iter, compile-time double buffer ----
  int t = 0;
  int pb = 0;
#pragma unroll 1
  for (; t + 1 < iters - 1; t += 2) {
    STEP(zl[0], zl[1]);
    STEP(zl[1], zl[0]);
  }
  if (t < iters - 1) {
    STEP(zl[0], zl[1]);
    pb = 1;
  }
  __syncthreads();

  // ---- decoder: D[o][m] = sum_k Wd[o][k] Z^T[k][m] + bd ----
  const __bf16* zf = zl[pb];
#pragma unroll
  for (int ot = 0; ot < 2; ++ot) {
    const int o = 32 * wn + 16 * ot + l15;
    const float4 bv = *(const float4*)(bd + 32 * wn + 16 * ot + 4 * quad);
    floatx4 acc = {bv.x, bv.y, bv.z, bv.w};
#pragma unroll
    for (int ks = 0; ks < 4; ++ks) {
      const float4* p = (const float4*)(Wd + o * 128 + 32 * ks + 8 * quad);
      const bf16x8 a = cvt_bf16x8(p[0], p[1]);
      const bf16x8 b = *(const bf16x8*)&zf[rdo + 32 * ks];
      acc = MFMA16(a, b, acc);
    }
    // reg i -> consecutive o: one dwordx4 global store
    float4 ov;
    ov.x = acc[0]; ov.y = acc[1]; ov.z = acc[2]; ov.w = acc[3];
    *(float4*)(out + (size_t)(row0 + ml) * 64 + 32 * wn + 16 * ot + 4 * quad) = ov;
  }
}

extern "C" void kernel_launch(void* const* d_in, const int* in_sizes, int n_in,
                              void* d_out, int out_size, void* d_ws, size_t ws_size,
                              hipStream_t stream) {
  const float* x  = (const float*)d_in[0];
  const float* Wz = (const float*)d_in[1];
  const float* Ux = (const float*)d_in[2];
  const float* b  = (const float*)d_in[3];
  const float* Wd = (const float*)d_in[4];
  const float* bd = (const float*)d_in[5];
  const int* n_it = (const int*)d_in[6];
  float* outp = (float*)d_out;
  (void)in_sizes; (void)n_in; (void)d_ws; (void)ws_size; (void)out_size;

  dim3 grid(kBsz / kTM);  // 8192 blocks of 256 threads
  deq_fused<<<grid, 256, 0, stream>>>(x, Wz, Ux, b, Wd, bd, n_it, outp);
}